// Round 1
// 68.011 us; speedup vs baseline: 1.0358x; 1.0358x over previous
//
#include <hip/hip_runtime.h>

// Gaussian splat renderer: B=2, 9 params x 32x32 gaussians -> [B,3,128,128].
//
// SINGLE fused kernel. Previous 2-kernel design fed the render loop over the
// scalar (SMEM) pipe from a global table; 32 concurrent per-wave record
// streams thrashed the scalar cache -> every s_load was an L2 hit (~350 cyc)
// and the 64-VGPR/SGPR cap kept the compiler from pipelining past it
// (render ~28us vs ~7us VALU floor). Now each block builds the full
// 1024-gaussian table for its batch in LDS (one gaussian per thread,
// redundant across blocks, ~0.1us), then renders with uniform-address LDS
// reads: hardware broadcast, conflict-free, ~120 cyc latency -> hidden by
// 8 waves/SIMD. Also removes the setup launch, the global table round-trip,
// and all d_ws usage.
//
// Math is bit-identical to the previously passing kernel (pair-blocked
// packed dual-FP32, exp2-folded exponent, inline transcendentals).

#define NB   2
#define NG   1024            // gaussians per batch (32*32)
#define HOUT 128
#define WOUT 128
#define PSTRIDE 20           // floats per gaussian-PAIR record (18 used + 2 pad)
#define NCHUNK 16

typedef float v2f __attribute__((ext_vector_type(2)));

__device__ __forceinline__ float fast_exp(float x) {
    // e^x = 2^(x*log2e); range here is moderate (params ~N(0,1))
    return __builtin_amdgcn_exp2f(x * 1.4426950408889634f);
}
__device__ __forceinline__ float fast_sigmoid(float x) {
    float e = __builtin_amdgcn_exp2f(-x * 1.4426950408889634f);
    return __builtin_amdgcn_rcpf(1.0f + e);
}
__device__ __forceinline__ float fast_tanh(float x) {
    // tanh(x) = 2*sigmoid(2x) - 1
    float e = __builtin_amdgcn_exp2f(-x * 2.8853900817779268f);
    return fmaf(2.0f, __builtin_amdgcn_rcpf(1.0f + e), -1.0f);
}

// blockDim = (64 pixels, 16 chunks). 256 blocks per batch (16384 px / 64).
// LDS: 40KB table + 16KB reduce = 56KB -> 2 blocks/CU; 64-VGPR cap keeps
// 32 waves/CU (8/SIMD).
__global__ __launch_bounds__(1024, 8) void gauss_fused(const float* __restrict__ params,
                                                       float* __restrict__ out) {
    __shared__ __align__(16) float gtab[(NG / 2) * PSTRIDE];  // 40 KB
    __shared__ float4 sred[1024];                             // 16 KB

    const int tx  = threadIdx.x;             // pixel lane   [0,64)
    const int ty  = threadIdx.y;             // chunk        [0,16)
    const int tid = ty * 64 + tx;
    const int blk = blockIdx.x;
    const int b   = blk >> 8;                // batch

    // ---------------- per-gaussian setup: thread tid -> gaussian tid -------
    {
        const int n = tid;
        const int gh = n >> 5;
        const int gw = n & 31;

        const float* P = params + b * 9 * NG + n;   // channel stride = 1024
        float p0 = P[0 * NG];
        float p1 = P[1 * NG];
        float p2 = P[2 * NG];
        float p3 = P[3 * NG];
        float p4 = P[4 * NG];
        float p5 = P[5 * NG];
        float p6 = P[6 * NG];
        float p7 = P[7 * NG];
        float p8 = P[8 * NG];

        // base_grid: linspace(-31/32, 31/32, 32) -> -0.96875 + i/16; offset 2/32
        float mux = -0.96875f + (float)gw * 0.0625f + fast_tanh(p0) * 0.0625f;
        float muy = -0.96875f + (float)gh * 0.0625f + fast_tanh(p1) * 0.0625f;

        // cov = L L^T + 1e-5 I,  L = [[e^a,0],[b,e^c]]
        float ea  = fast_exp(p2);
        float ec  = fast_exp(p4);
        float c00 = ea * ea + 1e-5f;
        float c01 = p3 * ea;
        float c11 = p3 * p3 + ec * ec + 1e-5f;
        float det = c00 * c11 - c01 * c01;
        float id  = 1.0f / det;            // exact divide: det can be ~1e-10
        float Sa  =  c11 * id;
        float Sb  = -c01 * id;
        float Sc  =  c00 * id;

        // exponent = -0.5*(Sa dx^2 + 2 Sb dx dy + Sc dy^2); fold -0.5*log2(e)
        // so the render loop computes exp2 directly.
        const float s = -0.72134752044448169f;   // -0.5 * log2(e)
        float A  = s * Sa;
        float B2 = 2.0f * s * Sb;
        float C  = s * Sc;

        float cr = fast_sigmoid(p5);
        float cg = fast_sigmoid(p6);
        float cb = fast_sigmoid(p7);
        float op = fast_sigmoid(p8);

        // pair-blocked layout: record (n>>1), half (n&1); field stride 2
        float* o = gtab + (n >> 1) * PSTRIDE + (n & 1);
        o[0]  = mux;  o[2]  = muy;  o[4]  = A;       o[6]  = B2;
        o[8]  = C;    o[10] = op;   o[12] = op * cr; o[14] = op * cg;
        o[16] = op * cb;
    }
    __syncthreads();

    // ---------------- render ----------------------------------------------
    const int pix = ((blk & 255) << 6) + tx;        // pixel in [0,16384)
    const int h = pix >> 7;
    const int w = pix & 127;
    const float px = -1.0f + (float)w * (2.0f / 127.0f);
    const float py = -1.0f + (float)h * (2.0f / 127.0f);
    const v2f px2 = {px, px};
    const v2f py2 = {py, py};

    // wave-uniform chunk base; LDS reads are same-address across lanes ->
    // hardware broadcast, no bank conflicts.
    const v2f* __restrict__ gp =
        (const v2f*)(gtab + ty * (NG / 2 / NCHUNK) * PSTRIDE);

    v2f wsum2 = {0.0f, 0.0f}, ar2 = {0.0f, 0.0f};
    v2f ag2   = {0.0f, 0.0f}, ab2 = {0.0f, 0.0f};

    #pragma unroll 2
    for (int j = 0; j < NG / 2 / NCHUNK; ++j) {     // 32 pair-iterations
        const v2f* __restrict__ r = gp + j * (PSTRIDE / 2);
        v2f mux2 = r[0], muy2 = r[1];
        v2f A2   = r[2], B22  = r[3], C2 = r[4];
        v2f op2  = r[5], ocr2 = r[6], ocg2 = r[7], ocb2 = r[8];

        v2f dx = px2 - mux2;
        v2f dy = py2 - muy2;
        // e2 = A dx^2 + B2 dx dy + C dy^2   (exp2-scaled, <= 0)
        v2f m  = A2 * dx;
        m      = __builtin_elementwise_fma(B22, dy, m);
        v2f t  = C2 * dy;
        v2f e2 = __builtin_elementwise_fma(t, dy, m * dx);
        e2 = __builtin_elementwise_max(e2, (v2f){-28.853900817779268f,
                                                 -28.853900817779268f});
        v2f k2 = {__builtin_amdgcn_exp2f(e2.x), __builtin_amdgcn_exp2f(e2.y)};

        wsum2 = __builtin_elementwise_fma(op2,  k2, wsum2);
        ar2   = __builtin_elementwise_fma(ocr2, k2, ar2);
        ag2   = __builtin_elementwise_fma(ocg2, k2, ag2);
        ab2   = __builtin_elementwise_fma(ocb2, k2, ab2);
    }

    sred[tid] = make_float4(wsum2.x + wsum2.y, ar2.x + ar2.y,
                            ag2.x + ag2.y,     ab2.x + ab2.y);
    __syncthreads();

    if (ty == 0) {
        float4 a = sred[tx];
        #pragma unroll
        for (int k2i = 1; k2i < NCHUNK; ++k2i) {
            float4 t = sred[k2i * 64 + tx];
            a.x += t.x; a.y += t.y; a.z += t.z; a.w += t.w;
        }
        float inv = 1.0f / (a.x + 1e-8f);
        float* ob = out + b * 3 * (HOUT * WOUT) + pix;
        ob[0]               = a.y * inv;
        ob[HOUT * WOUT]     = a.z * inv;
        ob[2 * HOUT * WOUT] = a.w * inv;
    }
}

extern "C" void kernel_launch(void* const* d_in, const int* in_sizes, int n_in,
                              void* d_out, int out_size, void* d_ws, size_t ws_size,
                              hipStream_t stream) {
    const float* params = (const float*)d_in[0];
    float* out = (float*)d_out;
    (void)d_ws; (void)ws_size;   // workspace intentionally unused

    hipLaunchKernelGGL(gauss_fused, dim3(NB * (HOUT * WOUT) / 64), dim3(64, 16),
                       0, stream, params, out);
}